// Round 2
// baseline (3165.059 us; speedup 1.0000x reference)
//
#include <hip/hip_runtime.h>
#include <hip/hip_bf16.h>

// B=2, N=1024, D=512, H=8, DH=64, HD=512, FF=2048, DEPTH=4.
// Dual-dtype: inputs/outputs are either all-bf16 or all-fp32; detected at
// runtime from ln1_g (== ones): word0 = 0x3F803F80 (bf16) vs 0x3F800000 (f32).
// Internals fp32. rel_shift folded into T-GEMM epilogue (scatter +=) so no Tb.
//
// ws layout (floats): xbuf 1M | xn 1M | qkv 3M + wsum 1M (h1 aliases these 4M)
//                     | Sc 16M | flag  => ~88 MB.

using bf16 = __hip_bfloat16;

__device__ __forceinline__ float ldsel(const void* p, size_t i, bool isbf) {
    return isbf ? __bfloat162float(((const bf16*)p)[i]) : ((const float*)p)[i];
}
__device__ __forceinline__ void stsel(void* p, size_t i, bool isbf, float v) {
    if (isbf) ((bf16*)p)[i] = __float2bfloat16(v);
    else      ((float*)p)[i] = v;
}

__global__ void detect_kernel(const unsigned int* __restrict__ g, int* __restrict__ flag) {
    if (threadIdx.x == 0) flag[0] = ((g[0] & 0xFFFFu) != 0u) ? 1 : 0;
}

__global__ __launch_bounds__(256) void cast_in(const void* __restrict__ in, float* __restrict__ out,
                                               int n, const int* __restrict__ flagp) {
    bool bf = flagp[0] != 0;
    int i = blockIdx.x * 256 + threadIdx.x;
    if (i < n) out[i] = ldsel(in, i, bf);
}
__global__ __launch_bounds__(256) void cast_out(const float* __restrict__ in, void* __restrict__ out,
                                                int n, const int* __restrict__ flagp) {
    bool bf = flagp[0] != 0;
    int i = blockIdx.x * 256 + threadIdx.x;
    if (i < n) stsel(out, i, bf, in[i]);
}

// ---------------- layernorm: one block per row, D=512 ----------------
__global__ __launch_bounds__(256) void ln_kernel(const float* __restrict__ x,
                                                 const void* __restrict__ g, long long goff,
                                                 const void* __restrict__ bta, long long boff,
                                                 float* __restrict__ out,
                                                 const int* __restrict__ flagp) {
    bool bf = flagp[0] != 0;
    int row = blockIdx.x;
    const float* xr = x + (size_t)row * 512;
    int tid = threadIdx.x;
    float v0 = xr[tid], v1 = xr[tid + 256];
    float s = v0 + v1, q = v0 * v0 + v1 * v1;
    #pragma unroll
    for (int off = 32; off; off >>= 1) {
        s += __shfl_down(s, off);
        q += __shfl_down(q, off);
    }
    __shared__ float ls[4], lq[4];
    int wid = tid >> 6, lane = tid & 63;
    if (lane == 0) { ls[wid] = s; lq[wid] = q; }
    __syncthreads();
    if (tid == 0) {
        float ts = ls[0] + ls[1] + ls[2] + ls[3];
        float tq = lq[0] + lq[1] + lq[2] + lq[3];
        float m = ts * (1.f / 512.f);
        float var = tq * (1.f / 512.f) - m * m;
        ls[0] = m; lq[0] = rsqrtf(var + 1e-5f);
    }
    __syncthreads();
    float m = ls[0], r = lq[0];
    out[(size_t)row * 512 + tid] =
        (v0 - m) * r * ldsel(g, goff + tid, bf) + ldsel(bta, boff + tid, bf);
    out[(size_t)row * 512 + tid + 256] =
        (v1 - m) * r * ldsel(g, goff + tid + 256, bf) + ldsel(bta, boff + tid + 256, bf);
}

// ---------------- generic tiled GEMM ----------------
// C[m,n] = sum_k A[m,k] * (BT ? B[n,k] : B[k,n]); 64x64 tile, BK=16, 256 thr.
// EPI: 0 plain store; 1 qkv (+bias_pf for n<512); 2 +bias+resid; 3 +bias,GELU;
//      4 rel_shift scatter: Sc[i,j] += v/3 at t=m*1025+n+1, i=(t>>10)-1, j=t&1023.
// BIN: B is an external input (dtype via flag); else fp32 ws.
template<bool BT, int EPI, bool BIN>
__global__ __launch_bounds__(256) void gemm_kernel(
    const float* __restrict__ A, int lda, long long sAb, long long sAh,
    const void* __restrict__ Bv, long long boff, int ldb, long long sBb, long long sBh,
    float* __restrict__ C, int ldc, long long sCb, long long sCh,
    int K,
    const void* __restrict__ bias, long long biasoff,
    const float* __restrict__ resid,
    const int* __restrict__ flagp) {
    bool flg = flagp[0] != 0;
    const bool bbf = BIN ? flg : false;
    int z = blockIdx.z, zb = z >> 3, zh = z & 7;
    A += (size_t)zb * sAb + (size_t)zh * sAh;
    size_t Bbase = (size_t)boff + (size_t)zb * sBb + (size_t)zh * sBh;
    C += (size_t)zb * sCb + (size_t)zh * sCh;
    if (EPI == 2) resid += (size_t)zb * sCb + (size_t)zh * sCh;

    const int tid = threadIdx.x;
    const int m0 = blockIdx.y * 64, n0 = blockIdx.x * 64;
    __shared__ float As[16][68];
    __shared__ float Bs[16][68];
    float acc[4][4] = {};
    const int ty = tid >> 4, tx = tid & 15;
    const int arow = tid >> 2, ac0 = (tid & 3) * 4;

    for (int k0 = 0; k0 < K; k0 += 16) {
        const float* Ap = A + (size_t)(m0 + arow) * lda + k0 + ac0;
        #pragma unroll
        for (int u = 0; u < 4; ++u) As[ac0 + u][arow] = Ap[u];
        if (!BT) {
            size_t bi = Bbase + (size_t)(k0 + (tid >> 4)) * ldb + n0 + (tid & 15) * 4;
            #pragma unroll
            for (int u = 0; u < 4; ++u) Bs[tid >> 4][(tid & 15) * 4 + u] = ldsel(Bv, bi + u, bbf);
        } else {
            size_t bi = Bbase + (size_t)(n0 + (tid >> 2)) * ldb + k0 + (tid & 3) * 4;
            #pragma unroll
            for (int u = 0; u < 4; ++u) Bs[(tid & 3) * 4 + u][tid >> 2] = ldsel(Bv, bi + u, bbf);
        }
        __syncthreads();
        #pragma unroll
        for (int kk = 0; kk < 16; ++kk) {
            float av[4], bv[4];
            #pragma unroll
            for (int i = 0; i < 4; ++i) av[i] = As[kk][ty * 4 + i];
            #pragma unroll
            for (int j = 0; j < 4; ++j) bv[j] = Bs[kk][tx * 4 + j];
            #pragma unroll
            for (int i = 0; i < 4; ++i)
                #pragma unroll
                for (int j = 0; j < 4; ++j)
                    acc[i][j] = fmaf(av[i], bv[j], acc[i][j]);
        }
        __syncthreads();
    }

    #pragma unroll
    for (int i = 0; i < 4; ++i) {
        int m = m0 + ty * 4 + i;
        #pragma unroll
        for (int j = 0; j < 4; ++j) {
            int n = n0 + tx * 4 + j;
            float v = acc[i][j];
            if (EPI == 4) {
                int t = m * 1025 + n + 1;
                int ii = (t >> 10) - 1;
                if (ii >= 0) C[(size_t)ii * 1024 + (t & 1023)] += v * (1.f / 3.f);
            } else {
                if (EPI == 1) { if (n < 512) v += ldsel(bias, biasoff + n, flg); }
                else if (EPI == 2) { v += ldsel(bias, biasoff + n, flg) + resid[(size_t)m * ldc + n]; }
                else if (EPI == 3) { v += ldsel(bias, biasoff + n, flg); v = 0.5f * v * (1.0f + erff(v * 0.70710678118f)); }
                C[(size_t)m * ldc + n] = v;
            }
        }
    }
}

// ---------------- wsum = r_t@w_kt + r_c@w_kc + r_p@w_kp (K=3*512) ----------------
__global__ __launch_bounds__(256) void gemm3_kernel(
    const void* __restrict__ A0, const void* __restrict__ A1, const void* __restrict__ A2,
    const void* __restrict__ B0, const void* __restrict__ B1, const void* __restrict__ B2,
    long long woff, float* __restrict__ C, const int* __restrict__ flagp) {
    bool bf = flagp[0] != 0;
    const int tid = threadIdx.x;
    const int m0 = blockIdx.y * 64, n0 = blockIdx.x * 64;
    __shared__ float As[16][68];
    __shared__ float Bs[16][68];
    float acc[4][4] = {};
    const int ty = tid >> 4, tx = tid & 15;
    for (int k0 = 0; k0 < 1536; k0 += 16) {
        int sel = k0 >> 9, kl = k0 & 511;
        const void* Ab = (sel == 0) ? A0 : ((sel == 1) ? A1 : A2);
        const void* Bb = (sel == 0) ? B0 : ((sel == 1) ? B1 : B2);
        size_t ai = (size_t)(m0 + (tid >> 2)) * 512 + kl + (tid & 3) * 4;
        #pragma unroll
        for (int u = 0; u < 4; ++u) As[(tid & 3) * 4 + u][tid >> 2] = ldsel(Ab, ai + u, bf);
        size_t bi = (size_t)woff + (size_t)(kl + (tid >> 4)) * 512 + n0 + (tid & 15) * 4;
        #pragma unroll
        for (int u = 0; u < 4; ++u) Bs[tid >> 4][(tid & 15) * 4 + u] = ldsel(Bb, bi + u, bf);
        __syncthreads();
        #pragma unroll
        for (int kk = 0; kk < 16; ++kk) {
            float av[4], bv[4];
            #pragma unroll
            for (int i = 0; i < 4; ++i) av[i] = As[kk][ty * 4 + i];
            #pragma unroll
            for (int j = 0; j < 4; ++j) bv[j] = Bs[kk][tx * 4 + j];
            #pragma unroll
            for (int i = 0; i < 4; ++i)
                #pragma unroll
                for (int j = 0; j < 4; ++j)
                    acc[i][j] = fmaf(av[i], bv[j], acc[i][j]);
        }
        __syncthreads();
    }
    #pragma unroll
    for (int i = 0; i < 4; ++i)
        #pragma unroll
        for (int j = 0; j < 4; ++j)
            C[(size_t)(m0 + ty * 4 + i) * 512 + n0 + tx * 4 + j] = acc[i][j];
}

// ---------------- dots*SCALE + softmax over h=8; attn in place; opt. out ----------------
__global__ __launch_bounds__(256) void combine_softmax_kernel(
    float* __restrict__ Sc, void* __restrict__ attn_out, long long ooff,
    const int* __restrict__ flagp) {
    bool bf = flagp[0] != 0;
    int id = blockIdx.x * 256 + threadIdx.x;     // 2*1024*1024 threads
    int j = id & 1023;
    int i = (id >> 10) & 1023;
    int b = id >> 20;
    size_t base = (size_t)b * 8388608 + (size_t)i * 1024 + j;
    float d[8];
    float mx = -3.4e38f;
    #pragma unroll
    for (int h = 0; h < 8; ++h) {
        float v = Sc[base + (size_t)h * 1048576] * 0.125f;   // SCALE = 64^-0.5
        d[h] = v;
        mx = fmaxf(mx, v);
    }
    float s = 0.f;
    #pragma unroll
    for (int h = 0; h < 8; ++h) { d[h] = __expf(d[h] - mx); s += d[h]; }
    float inv = 1.f / s;
    #pragma unroll
    for (int h = 0; h < 8; ++h) {
        float a = d[h] * inv;
        Sc[base + (size_t)h * 1048576] = a;
        if (attn_out) stsel(attn_out, (size_t)ooff + base + (size_t)h * 1048576, bf, a);
    }
}

extern "C" void kernel_launch(void* const* d_in, const int* in_sizes, int n_in,
                              void* d_out, int out_size, void* d_ws, size_t ws_size,
                              hipStream_t stream) {
    (void)in_sizes; (void)n_in; (void)out_size; (void)ws_size;
    const void* x_in    = d_in[0];
    const void* r_t     = d_in[1];
    const void* r_c     = d_in[2];
    const void* r_p     = d_in[3];
    const void* bias_pf = d_in[4];
    const void* ln1_g   = d_in[5];
    const void* ln1_b   = d_in[6];
    const void* w_qkv   = d_in[7];
    const void* w_outw  = d_in[8];
    const void* b_out   = d_in[9];
    const void* w_kt    = d_in[10];
    const void* w_kc    = d_in[11];
    const void* w_kp    = d_in[12];
    const void* ln2_g   = d_in[13];
    const void* ln2_b   = d_in[14];
    const void* w_ff1   = d_in[15];
    const void* b_ff1   = d_in[16];
    const void* w_ff2   = d_in[17];
    const void* b_ff2   = d_in[18];

    float* w    = (float*)d_ws;
    float* xbuf = w;                        // 1048576
    float* xn   = w + 1048576;              // 1048576
    float* qkv  = w + 2097152;              // 3145728
    float* wsum = w + 5242880;              // 1048576
    float* h1   = qkv;                      // alias: 4194304 (qkv+wsum, dead in FF)
    float* Sc   = w + 6291456;              // 16777216
    int*  flagp = (int*)(w + 23068672);

    dim3 blk(256);

    detect_kernel<<<1, 64, 0, stream>>>((const unsigned int*)ln1_g, flagp);
    cast_in<<<4096, blk, 0, stream>>>(x_in, xbuf, 1048576, flagp);

    for (int l = 0; l < 4; ++l) {
        // LN1
        ln_kernel<<<2048, blk, 0, stream>>>(xbuf, ln1_g, l * 512, ln1_b, l * 512, xn, flagp);
        // qkv = xn @ w_qkv[l]; q-part += bias_pf
        gemm_kernel<false, 1, true><<<dim3(24, 32, 1), blk, 0, stream>>>(
            xn, 512, 0, 0,
            w_qkv, (long long)l * 786432, 1536, 0, 0,
            qkv, 1536, 0, 0, 512, bias_pf, 0, nullptr, flagp);
        // wsum = r_t@w_kt + r_c@w_kc + r_p@w_kp
        gemm3_kernel<<<dim3(8, 32, 1), blk, 0, stream>>>(
            r_t, r_c, r_p, w_kt, w_kc, w_kp, (long long)l * 262144, wsum, flagp);
        // Sc[b,h,i,j] = q_i . k_j   (K=64, NT)
        gemm_kernel<true, 0, false><<<dim3(16, 16, 16), blk, 0, stream>>>(
            qkv, 1536, 1572864, 64,
            (const void*)(qkv + 512), 0, 1536, 1572864, 64,
            Sc, 1024, 8388608, 1048576, 64, nullptr, 0, nullptr, flagp);
        // Sc += rel_shift(q . wsum)/3  (K=64, NT, scatter epilogue)
        gemm_kernel<true, 4, false><<<dim3(16, 16, 16), blk, 0, stream>>>(
            qkv, 1536, 1572864, 64,
            (const void*)wsum, 0, 512, 524288, 64,
            Sc, 1024, 8388608, 1048576, 64, nullptr, 0, nullptr, flagp);
        // *SCALE + softmax over h; last layer writes attn to d_out
        combine_softmax_kernel<<<8192, blk, 0, stream>>>(
            Sc, (l == 3) ? d_out : nullptr, 1048576, flagp);
        // out[i, h*64+d] = attn @ v   (K=1024, NN) -> xn
        gemm_kernel<false, 0, false><<<dim3(1, 16, 16), blk, 0, stream>>>(
            Sc, 1024, 8388608, 1048576,
            (const void*)(qkv + 1024), 0, 1536, 1572864, 64,
            xn, 512, 524288, 64, 1024, nullptr, 0, nullptr, flagp);
        // x = out @ w_out[l] + b_out[l] + x
        gemm_kernel<false, 2, true><<<dim3(8, 32, 1), blk, 0, stream>>>(
            xn, 512, 0, 0,
            w_outw, (long long)l * 262144, 512, 0, 0,
            xbuf, 512, 0, 0, 512, b_out, l * 512, xbuf, flagp);
        // LN2
        ln_kernel<<<2048, blk, 0, stream>>>(xbuf, ln2_g, l * 512, ln2_b, l * 512, xn, flagp);
        // h1 = gelu(xn @ w_ff1[l] + b_ff1[l])
        gemm_kernel<false, 3, true><<<dim3(32, 32, 1), blk, 0, stream>>>(
            xn, 512, 0, 0,
            w_ff1, (long long)l * 1048576, 2048, 0, 0,
            h1, 2048, 0, 0, 512, b_ff1, l * 2048, nullptr, flagp);
        // x = h1 @ w_ff2[l] + b_ff2[l] + x
        gemm_kernel<false, 2, true><<<dim3(8, 32, 1), blk, 0, stream>>>(
            h1, 2048, 0, 0,
            w_ff2, (long long)l * 1048576, 512, 0, 0,
            xbuf, 512, 0, 0, 2048, b_ff2, l * 512, xbuf, flagp);
    }

    cast_out<<<4096, blk, 0, stream>>>(xbuf, d_out, 1048576, flagp);
}

// Round 3
// 1044.488 us; speedup vs baseline: 3.0303x; 3.0303x over previous
//
#include <hip/hip_runtime.h>
#include <hip/hip_bf16.h>

// B=2, N=1024, D=512, H=8, DH=64, HD=512, FF=2048, DEPTH=4.
// Dual-dtype IO (bf16 or fp32, runtime-detected from ln1_g word0).
// All GEMMs: bf16 MFMA 16x16x32, 64x64 tiles, fp32 accum. Residual fp32.
// Scores: T-GEMM scatter-stores rel_shift(BD)/3 (injective map) into bf16 Scb,
// then QK-GEMM read-add-writes final dots in place (diagonal j=i+1 = zeros set).

using bf16 = __hip_bfloat16;
typedef __attribute__((ext_vector_type(8))) short short8;
typedef __attribute__((ext_vector_type(4))) float float4v;

__device__ __forceinline__ float ldsel(const void* p, long long i, bool isbf) {
    return isbf ? __bfloat162float(((const bf16*)p)[i]) : ((const float*)p)[i];
}
__device__ __forceinline__ void stsel(void* p, long long i, bool isbf, float v) {
    if (isbf) ((bf16*)p)[i] = __float2bfloat16(v);
    else      ((float*)p)[i] = v;
}

__global__ void detect_kernel(const unsigned int* __restrict__ g, int* __restrict__ flag) {
    if (threadIdx.x == 0) flag[0] = ((g[0] & 0xFFFFu) != 0u) ? 1 : 0;
}

__global__ __launch_bounds__(256) void cast_in(const void* __restrict__ in, float* __restrict__ out,
                                               int n, const int* __restrict__ flagp) {
    bool bf = flagp[0] != 0;
    int i = blockIdx.x * 256 + threadIdx.x;
    if (i < n) out[i] = ldsel(in, i, bf);
}
__global__ __launch_bounds__(256) void cast_out(const float* __restrict__ in, void* __restrict__ out,
                                                int n, const int* __restrict__ flagp) {
    bool bf = flagp[0] != 0;
    int i = blockIdx.x * 256 + threadIdx.x;
    if (i < n) stsel(out, i, bf, in[i]);
}

// rcat[m, s*512 + k] = r_s[m, k]  (bf16)
__global__ __launch_bounds__(256) void rcat_kernel(const void* __restrict__ src, bf16* __restrict__ dst,
                                                   int s, const int* __restrict__ flagp) {
    bool bf = flagp[0] != 0;
    int i = blockIdx.x * 256 + threadIdx.x;   // 1M
    int m = i >> 9, k = i & 511;
    dst[(size_t)m * 1536 + s * 512 + k] = __float2bfloat16(ldsel(src, i, bf));
}

// out[n, k] (bf16, ld=ldo) = in[k, n] (flag dtype, ld=ldi); dims multiples of 64
__global__ __launch_bounds__(256) void transpose_kernel(
    const void* __restrict__ in, long long ioff, int ldi,
    bf16* __restrict__ out, int ldo, const int* __restrict__ flagp) {
    bool bf = flagp[0] != 0;
    __shared__ bf16 t[64][65];
    int n0 = blockIdx.x * 64, k0 = blockIdx.y * 64;
    int tid = threadIdx.x;
    #pragma unroll
    for (int p = 0; p < 16; ++p) {
        int e = tid + p * 256;
        int r = e >> 6, c = e & 63;
        t[r][c] = __float2bfloat16(ldsel(in, ioff + (long long)(k0 + r) * ldi + n0 + c, bf));
    }
    __syncthreads();
    #pragma unroll
    for (int p = 0; p < 16; ++p) {
        int e = tid + p * 256;
        int r = e >> 6, c = e & 63;
        out[(size_t)(n0 + r) * ldo + k0 + c] = t[c][r];
    }
}

// ---------------- layernorm: one block per row, D=512; fp32 in -> bf16 out ----------------
__global__ __launch_bounds__(256) void ln_kernel(const float* __restrict__ x,
                                                 const void* __restrict__ g, long long goff,
                                                 const void* __restrict__ bta, long long boff,
                                                 bf16* __restrict__ out,
                                                 const int* __restrict__ flagp) {
    bool bf = flagp[0] != 0;
    int row = blockIdx.x;
    const float* xr = x + (size_t)row * 512;
    int tid = threadIdx.x;
    float v0 = xr[tid], v1 = xr[tid + 256];
    float s = v0 + v1, q = v0 * v0 + v1 * v1;
    #pragma unroll
    for (int off = 32; off; off >>= 1) {
        s += __shfl_down(s, off);
        q += __shfl_down(q, off);
    }
    __shared__ float ls[4], lq[4];
    int wid = tid >> 6, lane = tid & 63;
    if (lane == 0) { ls[wid] = s; lq[wid] = q; }
    __syncthreads();
    if (tid == 0) {
        float ts = ls[0] + ls[1] + ls[2] + ls[3];
        float tq = lq[0] + lq[1] + lq[2] + lq[3];
        float m = ts * (1.f / 512.f);
        float var = tq * (1.f / 512.f) - m * m;
        ls[0] = m; lq[0] = rsqrtf(var + 1e-5f);
    }
    __syncthreads();
    float m = ls[0], r = lq[0];
    out[(size_t)row * 512 + tid] =
        __float2bfloat16((v0 - m) * r * ldsel(g, goff + tid, bf) + ldsel(bta, boff + tid, bf));
    out[(size_t)row * 512 + tid + 256] =
        __float2bfloat16((v1 - m) * r * ldsel(g, goff + tid + 256, bf) + ldsel(bta, boff + tid + 256, bf));
}

// ---------------- MFMA GEMM: C[m,n] = sum_k A[m,k]*B[n,k] (NT), bf16 in, fp32 acc ----------
// 64x64 tile, BK=32, 256 thr = 4 waves (2x2), wave = 32x32 = 2x2 mfma frags.
// EPI: 0 dots-combine: bf16 C[m,n] = v + (n==m+1 ? 0 : C[m,n])
//      1 qkv: n<512 -> bf16 C+bias_pf; n<1024 -> bf16 C; else vT[plane][d][i] = v
//      2 fp32 C[m,n] = v + bias[n] + resid[m,n]
//      3 bf16 C = gelu(v + bias[n])
//      4 rel-shift scatter-store: t=m*1025+n+1; bf16 C[ii,jj] = v/3 (ii>=0)
//      5 bf16 plain store
template<int EPI>
__global__ __launch_bounds__(256) void mgemm(
    const bf16* __restrict__ A, int lda, long long sAb, long long sAh,
    const bf16* __restrict__ B, int ldb, long long sBb, long long sBh,
    void* __restrict__ Cv, int ldc, long long sCb, long long sCh,
    int K,
    const void* __restrict__ bias, long long biasoff,
    float* __restrict__ resid,
    bf16* __restrict__ aux,
    const int* __restrict__ flagp) {
    const bool flg = flagp[0] != 0;
    const int tid = threadIdx.x;
    const int lane = tid & 63, wave = tid >> 6;
    const int m0 = blockIdx.y * 64, n0 = blockIdx.x * 64;
    const int zb = (int)(blockIdx.z >> 3), zh = (int)(blockIdx.z & 7);
    A += (size_t)zb * sAb + (size_t)zh * sAh;
    B += (size_t)zb * sBb + (size_t)zh * sBh;

    __shared__ bf16 As[64][40];
    __shared__ bf16 Bs[64][40];

    const int srow = tid >> 2, sk8 = (tid & 3) * 8;
    const bf16* Ap = A + (size_t)(m0 + srow) * lda + sk8;
    const bf16* Bp = B + (size_t)(n0 + srow) * ldb + sk8;

    const int wm = (wave >> 1) * 32, wn = (wave & 1) * 32;
    const int fr = lane & 15, fq = lane >> 4;

    float4v acc[2][2] = {};

    uint4 av = *(const uint4*)Ap;
    uint4 bv = *(const uint4*)Bp;

    for (int k0 = 0; k0 < K; k0 += 32) {
        __syncthreads();
        *(uint2*)&As[srow][sk8]     = make_uint2(av.x, av.y);
        *(uint2*)&As[srow][sk8 + 4] = make_uint2(av.z, av.w);
        *(uint2*)&Bs[srow][sk8]     = make_uint2(bv.x, bv.y);
        *(uint2*)&Bs[srow][sk8 + 4] = make_uint2(bv.z, bv.w);
        if (k0 + 32 < K) {
            av = *(const uint4*)(Ap + k0 + 32);
            bv = *(const uint4*)(Bp + k0 + 32);
        }
        __syncthreads();
        short8 af[2], bfr[2];
        #pragma unroll
        for (int f = 0; f < 2; ++f) {
            union { uint2 u[2]; short8 s; } ua, ub;
            const bf16* ap = &As[wm + f * 16 + fr][fq * 8];
            ua.u[0] = *(const uint2*)ap;
            ua.u[1] = *(const uint2*)(ap + 4);
            af[f] = ua.s;
            const bf16* bp = &Bs[wn + f * 16 + fr][fq * 8];
            ub.u[0] = *(const uint2*)bp;
            ub.u[1] = *(const uint2*)(bp + 4);
            bfr[f] = ub.s;
        }
        #pragma unroll
        for (int i = 0; i < 2; ++i)
            #pragma unroll
            for (int j = 0; j < 2; ++j)
                acc[i][j] = __builtin_amdgcn_mfma_f32_16x16x32_bf16(af[i], bfr[j], acc[i][j], 0, 0, 0);
    }

    const long long coff = (long long)zb * sCb + (long long)zh * sCh;
    #pragma unroll
    for (int i = 0; i < 2; ++i) {
        #pragma unroll
        for (int j = 0; j < 2; ++j) {
            #pragma unroll
            for (int r = 0; r < 4; ++r) {
                int m = m0 + wm + i * 16 + fq * 4 + r;
                int n = n0 + wn + j * 16 + fr;
                float v = acc[i][j][r];
                if (EPI == 0) {
                    bf16* C = (bf16*)Cv + coff;
                    float prev = (n == m + 1) ? 0.f : __bfloat162float(C[(size_t)m * ldc + n]);
                    C[(size_t)m * ldc + n] = __float2bfloat16(v + prev);
                } else if (EPI == 1) {
                    bf16* C = (bf16*)Cv;
                    if (n < 512) {
                        C[(size_t)m * ldc + n] = __float2bfloat16(v + ldsel(bias, biasoff + n, flg));
                    } else if (n < 1024) {
                        C[(size_t)m * ldc + n] = __float2bfloat16(v);
                    } else {
                        int h = (n >> 6) & 7, d = n & 63, ii = m & 1023, bb = m >> 10;
                        aux[(size_t)(bb * 8 + h) * 65536 + (size_t)d * 1024 + ii] = __float2bfloat16(v);
                    }
                } else if (EPI == 2) {
                    float* C = (float*)Cv;
                    C[(size_t)m * ldc + n] = v + ldsel(bias, biasoff + n, flg) + resid[(size_t)m * ldc + n];
                } else if (EPI == 3) {
                    bf16* C = (bf16*)Cv;
                    float t = v + ldsel(bias, biasoff + n, flg);
                    C[(size_t)m * ldc + n] = __float2bfloat16(0.5f * t * (1.f + erff(t * 0.70710678118f)));
                } else if (EPI == 4) {
                    bf16* C = (bf16*)Cv + coff;
                    int t = m * 1025 + n + 1;
                    int ii = (t >> 10) - 1;
                    if (ii >= 0) C[(size_t)ii * 1024 + (t & 1023)] = __float2bfloat16(v * (1.f / 3.f));
                } else if (EPI == 5) {
                    bf16* C = (bf16*)Cv + coff;
                    C[(size_t)m * ldc + n] = __float2bfloat16(v);
                }
            }
        }
    }
}

// ---------------- softmax over h=8; Scb bf16 -> attn bf16 (+ optional d_out) -------------
__global__ __launch_bounds__(256) void softmax_kernel(
    const bf16* __restrict__ Scb, bf16* __restrict__ attn,
    void* __restrict__ oattn, const int* __restrict__ flagp) {
    bool bf = flagp[0] != 0;
    int id = blockIdx.x * 256 + threadIdx.x;   // 2M threads
    int b = id >> 20;
    size_t base = (size_t)b * 8388608 + (size_t)(id & 1048575);
    float d[8];
    float mx = -3.4e38f;
    #pragma unroll
    for (int h = 0; h < 8; ++h) {
        float v = __bfloat162float(Scb[base + (size_t)h * 1048576]) * 0.125f;  // SCALE
        d[h] = v; mx = fmaxf(mx, v);
    }
    float s = 0.f;
    #pragma unroll
    for (int h = 0; h < 8; ++h) { d[h] = __expf(d[h] - mx); s += d[h]; }
    float inv = 1.f / s;
    #pragma unroll
    for (int h = 0; h < 8; ++h) {
        float a = d[h] * inv;
        attn[base + (size_t)h * 1048576] = __float2bfloat16(a);
        if (oattn) stsel(oattn, 1048576 + (long long)(base + (size_t)h * 1048576), bf, a);
    }
}

extern "C" void kernel_launch(void* const* d_in, const int* in_sizes, int n_in,
                              void* d_out, int out_size, void* d_ws, size_t ws_size,
                              hipStream_t stream) {
    (void)in_sizes; (void)n_in; (void)out_size; (void)ws_size;
    const void* x_in    = d_in[0];
    const void* r_t     = d_in[1];
    const void* r_c     = d_in[2];
    const void* r_p     = d_in[3];
    const void* bias_pf = d_in[4];
    const void* ln1_g   = d_in[5];
    const void* ln1_b   = d_in[6];
    const void* w_qkv   = d_in[7];
    const void* w_outw  = d_in[8];
    const void* b_out   = d_in[9];
    const void* w_kt    = d_in[10];
    const void* w_kc    = d_in[11];
    const void* w_kp    = d_in[12];
    const void* ln2_g   = d_in[13];
    const void* ln2_b   = d_in[14];
    const void* w_ff1   = d_in[15];
    const void* b_ff1   = d_in[16];
    const void* w_ff2   = d_in[17];
    const void* b_ff2   = d_in[18];

    float* xbuf  = (float*)d_ws;                 // 1M fp32
    bf16* base16 = (bf16*)(xbuf + 1048576);
    bf16* Scb  = base16;                         // 16M (h1 aliases first 4M)
    bf16* h1   = base16;
    bf16* attn = base16 + 16777216;              // 16M
    bf16* xnb  = attn + 16777216;                // 1M
    bf16* qkvb = xnb + 1048576;                  // 3M
    bf16* vT   = qkvb + 3145728;                 // 1M
    bf16* wsum = vT + 1048576;                   // 1M
    bf16* rcat = wsum + 1048576;                 // 3M
    bf16* qkvT = rcat + 3145728;                 // 768K
    bf16* wcatT= qkvT + 786432;                  // 768K
    bf16* outT = wcatT + 786432;                 // 256K
    bf16* ff1T = outT + 262144;                  // 1M
    bf16* ff2T = ff1T + 1048576;                 // 1M
    int*  flagp = (int*)(ff2T + 1048576);

    dim3 blk(256);

    detect_kernel<<<1, 64, 0, stream>>>((const unsigned int*)ln1_g, flagp);
    cast_in<<<4096, blk, 0, stream>>>(x_in, xbuf, 1048576, flagp);
    rcat_kernel<<<4096, blk, 0, stream>>>(r_t, rcat, 0, flagp);
    rcat_kernel<<<4096, blk, 0, stream>>>(r_c, rcat, 1, flagp);
    rcat_kernel<<<4096, blk, 0, stream>>>(r_p, rcat, 2, flagp);

    for (int l = 0; l < 4; ++l) {
        // per-layer weight transposes (bf16, NT-ready)
        transpose_kernel<<<dim3(24, 8), blk, 0, stream>>>(w_qkv, (long long)l * 786432, 1536, qkvT, 512, flagp);
        transpose_kernel<<<dim3(8, 8), blk, 0, stream>>>(w_kt, (long long)l * 262144, 512, wcatT + 0,    1536, flagp);
        transpose_kernel<<<dim3(8, 8), blk, 0, stream>>>(w_kc, (long long)l * 262144, 512, wcatT + 512,  1536, flagp);
        transpose_kernel<<<dim3(8, 8), blk, 0, stream>>>(w_kp, (long long)l * 262144, 512, wcatT + 1024, 1536, flagp);
        transpose_kernel<<<dim3(8, 8), blk, 0, stream>>>(w_outw, (long long)l * 262144, 512, outT, 512, flagp);
        transpose_kernel<<<dim3(32, 8), blk, 0, stream>>>(w_ff1, (long long)l * 1048576, 2048, ff1T, 512, flagp);
        transpose_kernel<<<dim3(8, 32), blk, 0, stream>>>(w_ff2, (long long)l * 1048576, 512, ff2T, 2048, flagp);

        // LN1 -> xnb (bf16)
        ln_kernel<<<2048, blk, 0, stream>>>(xbuf, ln1_g, l * 512, ln1_b, l * 512, xnb, flagp);
        // qkv = xnb @ qkvT^T; q += bias_pf; v written transposed to vT
        mgemm<1><<<dim3(24, 32, 1), blk, 0, stream>>>(
            xnb, 512, 0, 0, qkvT, 512, 0, 0,
            qkvb, 1536, 0, 0, 512, bias_pf, 0, nullptr, vT, flagp);
        // wsum = rcat @ wcatT^T
        mgemm<5><<<dim3(8, 32, 1), blk, 0, stream>>>(
            rcat, 1536, 0, 0, wcatT, 1536, 0, 0,
            wsum, 512, 0, 0, 1536, nullptr, 0, nullptr, nullptr, flagp);
        // Scb = rel_shift(q . wsum)/3  (scatter-store)
        mgemm<4><<<dim3(16, 16, 16), blk, 0, stream>>>(
            qkvb, 1536, 1572864, 64, wsum, 512, 524288, 64,
            Scb, 1024, 8388608, 1048576, 64, nullptr, 0, nullptr, nullptr, flagp);
        // Scb = q.k + Scb (skip diagonal j=i+1)
        mgemm<0><<<dim3(16, 16, 16), blk, 0, stream>>>(
            qkvb, 1536, 1572864, 64, qkvb + 512, 1536, 1572864, 64,
            Scb, 1024, 8388608, 1048576, 64, nullptr, 0, nullptr, nullptr, flagp);
        // softmax over h; layer 3 also writes d_out attn region
        softmax_kernel<<<8192, blk, 0, stream>>>(Scb, attn, (l == 3) ? d_out : nullptr, flagp);
        // out = attn @ vT^T -> xnb
        mgemm<5><<<dim3(1, 16, 16), blk, 0, stream>>>(
            attn, 1024, 8388608, 1048576, vT, 1024, 524288, 65536,
            xnb, 512, 524288, 64, 1024, nullptr, 0, nullptr, nullptr, flagp);
        // x = out @ outT^T + b_out + x  (fp32)
        mgemm<2><<<dim3(8, 32, 1), blk, 0, stream>>>(
            xnb, 512, 0, 0, outT, 512, 0, 0,
            xbuf, 512, 0, 0, 512, b_out, (long long)l * 512, xbuf, nullptr, flagp);
        // LN2 -> xnb
        ln_kernel<<<2048, blk, 0, stream>>>(xbuf, ln2_g, l * 512, ln2_b, l * 512, xnb, flagp);
        // h1 = gelu(xnb @ ff1T^T + b_ff1)
        mgemm<3><<<dim3(32, 32, 1), blk, 0, stream>>>(
            xnb, 512, 0, 0, ff1T, 512, 0, 0,
            h1, 2048, 0, 0, 512, b_ff1, (long long)l * 2048, nullptr, nullptr, flagp);
        // x = h1 @ ff2T^T + b_ff2 + x  (fp32)
        mgemm<2><<<dim3(8, 32, 1), blk, 0, stream>>>(
            h1, 2048, 0, 0, ff2T, 2048, 0, 0,
            xbuf, 512, 0, 0, 2048, b_ff2, (long long)l * 512, xbuf, nullptr, flagp);
    }

    cast_out<<<4096, blk, 0, stream>>>(xbuf, d_out, 1048576, flagp);
}

// Round 4
// 998.381 us; speedup vs baseline: 3.1702x; 1.0462x over previous
//
#include <hip/hip_runtime.h>
#include <hip/hip_bf16.h>

// B=2, N=1024, D=512, H=8, DH=64, HD=512, FF=2048, DEPTH=4.
// Dual-dtype IO (bf16 or fp32, runtime-detected from ln1_g word0).
// bf16 MFMA 16x16x32 everywhere, fp32 accum, fp32 residual chain.
// Scores: BD scatter-stored (rel_shift, injective, diag = zero set) into Scb;
// fused kernel: AC mfma (8 h-planes in regs) + Scb add + softmax-over-h -> attn.

using bf16 = __hip_bfloat16;
typedef __attribute__((ext_vector_type(8))) short short8;
typedef __attribute__((ext_vector_type(4))) float float4v;

__device__ __forceinline__ float ldsel(const void* p, long long i, bool isbf) {
    return isbf ? __bfloat162float(((const bf16*)p)[i]) : ((const float*)p)[i];
}
__device__ __forceinline__ void stsel(void* p, long long i, bool isbf, float v) {
    if (isbf) ((bf16*)p)[i] = __float2bfloat16(v);
    else      ((float*)p)[i] = v;
}

__global__ void detect_kernel(const unsigned int* __restrict__ g, int* __restrict__ flag) {
    if (threadIdx.x == 0) flag[0] = ((g[0] & 0xFFFFu) != 0u) ? 1 : 0;
}

__global__ __launch_bounds__(256) void cast_in(const void* __restrict__ in, float* __restrict__ out,
                                               int n, const int* __restrict__ flagp) {
    bool bf = flagp[0] != 0;
    int i = blockIdx.x * 256 + threadIdx.x;
    if (i < n) out[i] = ldsel(in, i, bf);
}
__global__ __launch_bounds__(256) void cast_out(const float* __restrict__ in, void* __restrict__ out,
                                                int n, const int* __restrict__ flagp) {
    bool bf = flagp[0] != 0;
    int i = blockIdx.x * 256 + threadIdx.x;
    if (i < n) stsel(out, i, bf, in[i]);
}

// rcat[m, s*512+k] = r_s[m,k], s = blockIdx.y
__global__ __launch_bounds__(256) void rcat_all(const void* __restrict__ r0, const void* __restrict__ r1,
                                                const void* __restrict__ r2, bf16* __restrict__ dst,
                                                const int* __restrict__ flagp) {
    bool bf = flagp[0] != 0;
    int s = blockIdx.y;
    const void* src = (s == 0) ? r0 : ((s == 1) ? r1 : r2);
    int i = blockIdx.x * 256 + threadIdx.x;   // 1M
    int m = i >> 9, k = i & 511;
    dst[(size_t)m * 1536 + s * 512 + k] = __float2bfloat16(ldsel(src, i, bf));
}

// ---- all weight transposes (all 4 layers) in ONE dispatch ----
struct TJobs {
    int src[28]; int srcoff[28]; int ldi[28];
    int dstoff[28]; int ldo[28]; int tx[28]; int ty[28];
};
__global__ __launch_bounds__(256) void prep_weights(
    const void* __restrict__ s0, const void* __restrict__ s1, const void* __restrict__ s2,
    const void* __restrict__ s3, const void* __restrict__ s4, const void* __restrict__ s5,
    const void* __restrict__ s6, TJobs jobs, bf16* __restrict__ arena,
    const int* __restrict__ flagp) {
    bool bf = flagp[0] != 0;
    int z = blockIdx.z;
    if ((int)blockIdx.x >= jobs.tx[z] || (int)blockIdx.y >= jobs.ty[z]) return;
    int sid = jobs.src[z];
    const void* in = (sid == 0) ? s0 : (sid == 1) ? s1 : (sid == 2) ? s2 :
                     (sid == 3) ? s3 : (sid == 4) ? s4 : (sid == 5) ? s5 : s6;
    long long ioff = jobs.srcoff[z];
    int ldi = jobs.ldi[z], ldo = jobs.ldo[z];
    bf16* out = arena + jobs.dstoff[z];
    __shared__ bf16 t[64][65];
    int n0 = blockIdx.x * 64, k0 = blockIdx.y * 64;
    int tid = threadIdx.x;
    #pragma unroll
    for (int p = 0; p < 16; ++p) {
        int e = tid + p * 256;
        int r = e >> 6, c = e & 63;
        t[r][c] = __float2bfloat16(ldsel(in, ioff + (long long)(k0 + r) * ldi + n0 + c, bf));
    }
    __syncthreads();
    #pragma unroll
    for (int p = 0; p < 16; ++p) {
        int e = tid + p * 256;
        int r = e >> 6, c = e & 63;
        out[(size_t)(n0 + r) * ldo + k0 + c] = t[c][r];
    }
}

// ---- layernorm: one block per row, D=512; fp32 in -> bf16 out ----
__global__ __launch_bounds__(256) void ln_kernel(const float* __restrict__ x,
                                                 const void* __restrict__ g, long long goff,
                                                 const void* __restrict__ bta, long long boff,
                                                 bf16* __restrict__ out,
                                                 const int* __restrict__ flagp) {
    bool bf = flagp[0] != 0;
    int row = blockIdx.x;
    const float* xr = x + (size_t)row * 512;
    int tid = threadIdx.x;
    float v0 = xr[tid], v1 = xr[tid + 256];
    float s = v0 + v1, q = v0 * v0 + v1 * v1;
    #pragma unroll
    for (int off = 32; off; off >>= 1) {
        s += __shfl_down(s, off);
        q += __shfl_down(q, off);
    }
    __shared__ float ls[4], lq[4];
    int wid = tid >> 6, lane = tid & 63;
    if (lane == 0) { ls[wid] = s; lq[wid] = q; }
    __syncthreads();
    if (tid == 0) {
        float ts = ls[0] + ls[1] + ls[2] + ls[3];
        float tq = lq[0] + lq[1] + lq[2] + lq[3];
        float m = ts * (1.f / 512.f);
        float var = tq * (1.f / 512.f) - m * m;
        ls[0] = m; lq[0] = rsqrtf(var + 1e-5f);
    }
    __syncthreads();
    float m = ls[0], r = lq[0];
    out[(size_t)row * 512 + tid] =
        __float2bfloat16((v0 - m) * r * ldsel(g, goff + tid, bf) + ldsel(bta, boff + tid, bf));
    out[(size_t)row * 512 + tid + 256] =
        __float2bfloat16((v1 - m) * r * ldsel(g, goff + tid + 256, bf) + ldsel(bta, boff + tid + 256, bf));
}

// ---- MFMA GEMM: C[m,n] = sum_k A[m,k]*B[n,k] (NT). 128x64 tile, BK=32. ----
// 4 waves (2x2): wave tile 64x32 = 4x2 frags of 16x16x32.
// EPI: 1 qkv (n<512: +bias_pf; n<1024: k; else vT scatter); 2 fp32 +bias+resid;
//      3 bf16 gelu(+bias); 4 rel-shift scatter-store v/3; 5 bf16 plain store.
template<int EPI>
__global__ __launch_bounds__(256) void mgemm(
    const bf16* __restrict__ A, int lda, long long sAb, long long sAh,
    const bf16* __restrict__ B, int ldb, long long sBb, long long sBh,
    void* __restrict__ Cv, int ldc, long long sCb, long long sCh,
    int K,
    const void* __restrict__ bias, long long biasoff,
    float* __restrict__ resid,
    bf16* __restrict__ aux,
    const int* __restrict__ flagp) {
    const bool flg = flagp[0] != 0;
    const int tid = threadIdx.x;
    const int lane = tid & 63, wave = tid >> 6;
    const int m0 = blockIdx.y * 128, n0 = blockIdx.x * 64;
    const int zb = (int)(blockIdx.z >> 3), zh = (int)(blockIdx.z & 7);
    A += (size_t)zb * sAb + (size_t)zh * sAh;
    B += (size_t)zb * sBb + (size_t)zh * sBh;

    __shared__ bf16 As[128][40];
    __shared__ bf16 Bs[64][40];

    const int ar = tid >> 2, ak = (tid & 3) * 8;
    const bf16* Ap0 = A + (size_t)(m0 + ar) * lda + ak;
    const bf16* Ap1 = Ap0 + (size_t)64 * lda;
    const bf16* Bp  = B + (size_t)(n0 + ar) * ldb + ak;

    const int wm = (wave >> 1) * 64, wn = (wave & 1) * 32;
    const int fr = lane & 15, fq = lane >> 4;

    float4v acc[4][2] = {};

    uint4 a0 = *(const uint4*)Ap0;
    uint4 a1 = *(const uint4*)Ap1;
    uint4 b0 = *(const uint4*)Bp;

    for (int k0 = 0; k0 < K; k0 += 32) {
        __syncthreads();
        *(uint4*)&As[ar][ak]      = a0;
        *(uint4*)&As[ar + 64][ak] = a1;
        *(uint4*)&Bs[ar][ak]      = b0;
        if (k0 + 32 < K) {
            a0 = *(const uint4*)(Ap0 + k0 + 32);
            a1 = *(const uint4*)(Ap1 + k0 + 32);
            b0 = *(const uint4*)(Bp + k0 + 32);
        }
        __syncthreads();
        union { uint4 u; short8 s; } ua[4], ub[2];
        #pragma unroll
        for (int i = 0; i < 4; ++i) ua[i].u = *(const uint4*)&As[wm + i * 16 + fr][fq * 8];
        #pragma unroll
        for (int j = 0; j < 2; ++j) ub[j].u = *(const uint4*)&Bs[wn + j * 16 + fr][fq * 8];
        #pragma unroll
        for (int i = 0; i < 4; ++i)
            #pragma unroll
            for (int j = 0; j < 2; ++j)
                acc[i][j] = __builtin_amdgcn_mfma_f32_16x16x32_bf16(ua[i].s, ub[j].s, acc[i][j], 0, 0, 0);
    }

    const long long coff = (long long)zb * sCb + (long long)zh * sCh;
    #pragma unroll
    for (int i = 0; i < 4; ++i) {
        #pragma unroll
        for (int j = 0; j < 2; ++j) {
            #pragma unroll
            for (int r = 0; r < 4; ++r) {
                int m = m0 + wm + i * 16 + fq * 4 + r;
                int n = n0 + wn + j * 16 + fr;
                float v = acc[i][j][r];
                if (EPI == 1) {
                    bf16* C = (bf16*)Cv;
                    if (n < 512) {
                        C[(size_t)m * ldc + n] = __float2bfloat16(v + ldsel(bias, biasoff + n, flg));
                    } else if (n < 1024) {
                        C[(size_t)m * ldc + n] = __float2bfloat16(v);
                    } else {
                        int h = (n >> 6) & 7, d = n & 63, ii = m & 1023, bb = m >> 10;
                        aux[(size_t)(bb * 8 + h) * 65536 + (size_t)d * 1024 + ii] = __float2bfloat16(v);
                    }
                } else if (EPI == 2) {
                    float* C = (float*)Cv;
                    C[(size_t)m * ldc + n] = v + ldsel(bias, biasoff + n, flg) + resid[(size_t)m * ldc + n];
                } else if (EPI == 3) {
                    bf16* C = (bf16*)Cv;
                    float t = v + ldsel(bias, biasoff + n, flg);
                    C[(size_t)m * ldc + n] = __float2bfloat16(0.5f * t * (1.f + erff(t * 0.70710678118f)));
                } else if (EPI == 4) {
                    bf16* C = (bf16*)Cv + coff;
                    int t = m * 1025 + n + 1;
                    int ii = (t >> 10) - 1;
                    if (ii >= 0) C[(size_t)ii * 1024 + (t & 1023)] = __float2bfloat16(v * (1.f / 3.f));
                } else if (EPI == 5) {
                    bf16* C = (bf16*)Cv + coff;
                    C[(size_t)m * ldc + n] = __float2bfloat16(v);
                }
            }
        }
    }
}

// ---- fused AC + BD + softmax-over-h: block = 64x64 (i,j) tile, loops h=0..7 ----
// acc[h] kept in registers (8 * 2x2 frags). dots = (AC + Scb)*0.125 (diag: Scb=0).
__global__ __launch_bounds__(256) void scores_kernel(
    const bf16* __restrict__ qkvb, const bf16* __restrict__ Scb,
    bf16* __restrict__ attn, void* __restrict__ oattn, const int* __restrict__ flagp) {
    const bool bf = flagp[0] != 0;
    const int tid = threadIdx.x;
    const int lane = tid & 63, wave = tid >> 6;
    const int j0 = blockIdx.x * 64, i0 = blockIdx.y * 64, b = blockIdx.z;

    __shared__ bf16 Qs[64][72];
    __shared__ bf16 Ks[64][72];

    const int r0 = tid >> 3, c0 = (tid & 7) * 8;      // slots tid, tid+256 -> rows r0, r0+32
    const bf16* Qp = qkvb + (size_t)(b * 1024 + i0 + r0) * 1536 + c0;
    const bf16* Kp = qkvb + (size_t)(b * 1024 + j0 + r0) * 1536 + 512 + c0;

    const int wm = (wave >> 1) * 32, wn = (wave & 1) * 32;
    const int fr = lane & 15, fq = lane >> 4;

    float4v acc[8][2][2] = {};

    for (int h = 0; h < 8; ++h) {
        __syncthreads();
        *(uint4*)&Qs[r0][c0]      = *(const uint4*)(Qp + h * 64);
        *(uint4*)&Qs[r0 + 32][c0] = *(const uint4*)(Qp + (size_t)32 * 1536 + h * 64);
        *(uint4*)&Ks[r0][c0]      = *(const uint4*)(Kp + h * 64);
        *(uint4*)&Ks[r0 + 32][c0] = *(const uint4*)(Kp + (size_t)32 * 1536 + h * 64);
        __syncthreads();
        #pragma unroll
        for (int ks = 0; ks < 2; ++ks) {
            union { uint4 u; short8 s; } ua[2], ub[2];
            #pragma unroll
            for (int i = 0; i < 2; ++i) ua[i].u = *(const uint4*)&Qs[wm + i * 16 + fr][fq * 8 + ks * 32];
            #pragma unroll
            for (int j = 0; j < 2; ++j) ub[j].u = *(const uint4*)&Ks[wn + j * 16 + fr][fq * 8 + ks * 32];
            #pragma unroll
            for (int i = 0; i < 2; ++i)
                #pragma unroll
                for (int j = 0; j < 2; ++j)
                    acc[h][i][j] = __builtin_amdgcn_mfma_f32_16x16x32_bf16(ua[i].s, ub[j].s, acc[h][i][j], 0, 0, 0);
        }
    }

    const size_t pb = (size_t)b * 8388608;
    #pragma unroll
    for (int i = 0; i < 2; ++i) {
        #pragma unroll
        for (int j = 0; j < 2; ++j) {
            #pragma unroll
            for (int r = 0; r < 4; ++r) {
                int gi = i0 + wm + i * 16 + fq * 4 + r;
                int gj = j0 + wn + j * 16 + fr;
                size_t idx = pb + (size_t)gi * 1024 + gj;
                float d[8];
                float mx = -3.4e38f;
                #pragma unroll
                for (int h = 0; h < 8; ++h) {
                    float bd = (gj == gi + 1) ? 0.f
                               : __bfloat162float(Scb[idx + (size_t)h * 1048576]);
                    float v = (acc[h][i][j][r] + bd) * 0.125f;
                    d[h] = v; mx = fmaxf(mx, v);
                }
                float s = 0.f;
                #pragma unroll
                for (int h = 0; h < 8; ++h) { d[h] = __expf(d[h] - mx); s += d[h]; }
                float inv = 1.f / s;
                #pragma unroll
                for (int h = 0; h < 8; ++h) {
                    float a = d[h] * inv;
                    attn[idx + (size_t)h * 1048576] = __float2bfloat16(a);
                    if (oattn) stsel(oattn, 1048576 + (long long)(idx + (size_t)h * 1048576), bf, a);
                }
            }
        }
    }
}

extern "C" void kernel_launch(void* const* d_in, const int* in_sizes, int n_in,
                              void* d_out, int out_size, void* d_ws, size_t ws_size,
                              hipStream_t stream) {
    (void)in_sizes; (void)n_in; (void)out_size; (void)ws_size;
    const void* x_in    = d_in[0];
    const void* r_t     = d_in[1];
    const void* r_c     = d_in[2];
    const void* r_p     = d_in[3];
    const void* bias_pf = d_in[4];
    const void* ln1_g   = d_in[5];
    const void* ln1_b   = d_in[6];
    const void* w_qkv   = d_in[7];
    const void* w_outw  = d_in[8];
    const void* b_out   = d_in[9];
    const void* w_kt    = d_in[10];
    const void* w_kc    = d_in[11];
    const void* w_kp    = d_in[12];
    const void* ln2_g   = d_in[13];
    const void* ln2_b   = d_in[14];
    const void* w_ff1   = d_in[15];
    const void* b_ff1   = d_in[16];
    const void* w_ff2   = d_in[17];
    const void* b_ff2   = d_in[18];

    float* xbuf  = (float*)d_ws;                 // 1M fp32
    bf16* base16 = (bf16*)(xbuf + 1048576);
    bf16* Scb   = base16;                        // 16M (h1 aliases first 4M)
    bf16* h1    = base16;
    bf16* attn  = base16 + 16777216;             // 16M
    bf16* xnb   = attn + 16777216;               // 1M
    bf16* qkvb  = xnb + 1048576;                 // 3M
    bf16* vT    = qkvb + 3145728;                // 1M
    bf16* wsum  = vT + 1048576;                  // 1M
    bf16* rcat  = wsum + 1048576;                // 3M
    bf16* arena = rcat + 3145728;                // 15.75M (4 layers' transposed W)
    int*  flagp = (int*)(arena + 15728640);

    const int LW = 3932160;                      // arena stride per layer
    const int QKV_O = 0, WCAT_O = 786432, OUT_O = 1572864, FF1_O = 1835008, FF2_O = 2883584;

    dim3 blk(256);

    detect_kernel<<<1, 64, 0, stream>>>((const unsigned int*)ln1_g, flagp);
    cast_in<<<4096, blk, 0, stream>>>(x_in, xbuf, 1048576, flagp);
    rcat_all<<<dim3(4096, 3), blk, 0, stream>>>(r_t, r_c, r_p, rcat, flagp);

    // all weight transposes in one dispatch
    TJobs jobs;
    int z = 0;
    for (int l = 0; l < 4; ++l) {
        int L = l * LW;
        // qkvT: out 1536x512 <- w_qkv[l] (512x1536)
        jobs.src[z]=0; jobs.srcoff[z]=l*786432;  jobs.ldi[z]=1536; jobs.dstoff[z]=L+QKV_O;      jobs.ldo[z]=512;  jobs.tx[z]=24; jobs.ty[z]=8;  ++z;
        // wcatT cols: out 512x1536 (three 512-col slabs) <- w_k{t,c,p}[l] (512x512)
        jobs.src[z]=1; jobs.srcoff[z]=l*262144;  jobs.ldi[z]=512;  jobs.dstoff[z]=L+WCAT_O;     jobs.ldo[z]=1536; jobs.tx[z]=8;  jobs.ty[z]=8;  ++z;
        jobs.src[z]=2; jobs.srcoff[z]=l*262144;  jobs.ldi[z]=512;  jobs.dstoff[z]=L+WCAT_O+512; jobs.ldo[z]=1536; jobs.tx[z]=8;  jobs.ty[z]=8;  ++z;
        jobs.src[z]=3; jobs.srcoff[z]=l*262144;  jobs.ldi[z]=512;  jobs.dstoff[z]=L+WCAT_O+1024;jobs.ldo[z]=1536; jobs.tx[z]=8;  jobs.ty[z]=8;  ++z;
        // outT: 512x512
        jobs.src[z]=4; jobs.srcoff[z]=l*262144;  jobs.ldi[z]=512;  jobs.dstoff[z]=L+OUT_O;      jobs.ldo[z]=512;  jobs.tx[z]=8;  jobs.ty[z]=8;  ++z;
        // ff1T: out 2048x512 <- w_ff1[l] (512x2048)
        jobs.src[z]=5; jobs.srcoff[z]=l*1048576; jobs.ldi[z]=2048; jobs.dstoff[z]=L+FF1_O;      jobs.ldo[z]=512;  jobs.tx[z]=32; jobs.ty[z]=8;  ++z;
        // ff2T: out 512x2048 <- w_ff2[l] (2048x512)
        jobs.src[z]=6; jobs.srcoff[z]=l*1048576; jobs.ldi[z]=512;  jobs.dstoff[z]=L+FF2_O;      jobs.ldo[z]=2048; jobs.tx[z]=8;  jobs.ty[z]=32; ++z;
    }
    prep_weights<<<dim3(32, 32, 28), blk, 0, stream>>>(
        w_qkv, w_kt, w_kc, w_kp, w_outw, w_ff1, w_ff2, jobs, arena, flagp);

    for (int l = 0; l < 4; ++l) {
        const bf16* qkvT  = arena + l * LW + QKV_O;
        const bf16* wcatT = arena + l * LW + WCAT_O;
        const bf16* outT  = arena + l * LW + OUT_O;
        const bf16* ff1T  = arena + l * LW + FF1_O;
        const bf16* ff2T  = arena + l * LW + FF2_O;

        // LN1 -> xnb (bf16)
        ln_kernel<<<2048, blk, 0, stream>>>(xbuf, ln1_g, l * 512, ln1_b, l * 512, xnb, flagp);
        // qkv = xnb @ qkvT^T; q += bias_pf; v -> vT
        mgemm<1><<<dim3(24, 16, 1), blk, 0, stream>>>(
            xnb, 512, 0, 0, qkvT, 512, 0, 0,
            qkvb, 1536, 0, 0, 512, bias_pf, 0, nullptr, vT, flagp);
        // wsum = rcat @ wcatT^T
        mgemm<5><<<dim3(8, 16, 1), blk, 0, stream>>>(
            rcat, 1536, 0, 0, wcatT, 1536, 0, 0,
            wsum, 512, 0, 0, 1536, nullptr, 0, nullptr, nullptr, flagp);
        // Scb = rel_shift(q . wsum)/3 (scatter-store)
        mgemm<4><<<dim3(16, 8, 16), blk, 0, stream>>>(
            qkvb, 1536, 1572864, 64, wsum, 512, 524288, 64,
            Scb, 1024, 8388608, 1048576, 64, nullptr, 0, nullptr, nullptr, flagp);
        // fused AC + BD + softmax -> attn (+ d_out attn region on l=3)
        scores_kernel<<<dim3(16, 16, 2), blk, 0, stream>>>(
            qkvb, Scb, attn, (l == 3) ? d_out : nullptr, flagp);
        // out = attn @ vT^T -> xnb
        mgemm<5><<<dim3(1, 8, 16), blk, 0, stream>>>(
            attn, 1024, 8388608, 1048576, vT, 1024, 524288, 65536,
            xnb, 512, 524288, 64, 1024, nullptr, 0, nullptr, nullptr, flagp);
        // x = out @ outT^T + b_out + x (fp32)
        mgemm<2><<<dim3(8, 16, 1), blk, 0, stream>>>(
            xnb, 512, 0, 0, outT, 512, 0, 0,
            xbuf, 512, 0, 0, 512, b_out, (long long)l * 512, xbuf, nullptr, flagp);
        // LN2 -> xnb
        ln_kernel<<<2048, blk, 0, stream>>>(xbuf, ln2_g, l * 512, ln2_b, l * 512, xnb, flagp);
        // h1 = gelu(xnb @ ff1T^T + b_ff1)
        mgemm<3><<<dim3(32, 16, 1), blk, 0, stream>>>(
            xnb, 512, 0, 0, ff1T, 512, 0, 0,
            h1, 2048, 0, 0, 512, b_ff1, (long long)l * 2048, nullptr, nullptr, flagp);
        // x = h1 @ ff2T^T + b_ff2 + x (fp32)
        mgemm<2><<<dim3(8, 16, 1), blk, 0, stream>>>(
            h1, 2048, 0, 0, ff2T, 2048, 0, 0,
            xbuf, 512, 0, 0, 2048, b_ff2, (long long)l * 512, xbuf, nullptr, flagp);
    }

    cast_out<<<4096, blk, 0, stream>>>(xbuf, d_out, 1048576, flagp);
}